// Round 1
// baseline (360.885 us; speedup 1.0000x reference)
//
#include <hip/hip_runtime.h>

#define NN 262144
#define RANK 16
#define NNZ_K 1310720
#define NB 640           // k_bin blocks
#define BPB 2048         // nnz per k_bin block
#define NBKT 256         // row buckets (1024 rows each)
#define RPB 1024         // rows per bucket

struct P8 { const float* p[8]; };

// ---------------------------------------------------------------------------
// K1: per-chunk partials  part[l][c][r] = sum_{j in chunk c} v_l[j][r]*z[j]
// 512 threads/block (16 waves/CU), 8 independent float4 loads per iteration.
// ---------------------------------------------------------------------------
__global__ __launch_bounds__(512) void k_levels_t(P8 v, const float* __restrict__ z,
                                                  float* __restrict__ part) {
    __shared__ float zl[512];
    __shared__ float red[8][8][16];   // [level][wave][rank]
    const int tid  = threadIdx.x;
    const int base = blockIdx.x * 512;

    zl[tid] = z[base + tid];
    __syncthreads();

    const int q = tid & 3;
    const int e = tid >> 2;           // 0..127

    float4 acc[8];
#pragma unroll
    for (int l = 0; l < 8; ++l) acc[l] = make_float4(0.f, 0.f, 0.f, 0.f);

#pragma unroll
    for (int it = 0; it < 4; ++it) {
        const int jloc = it * 128 + e;
        const size_t j = (size_t)(base + jloc);
        const float zz = zl[jloc];
        float4 vv[8];
#pragma unroll
        for (int l = 0; l < 8; ++l)
            vv[l] = *(const float4*)(v.p[l] + j * RANK + q * 4);
#pragma unroll
        for (int l = 0; l < 8; ++l) {
            acc[l].x += vv[l].x * zz;
            acc[l].y += vv[l].y * zz;
            acc[l].z += vv[l].z * zz;
            acc[l].w += vv[l].w * zz;
        }
    }

    const int lane = tid & 63;
    const int wv   = tid >> 6;        // 0..7
#pragma unroll
    for (int l = 0; l < 8; ++l) {
        float4 a = acc[l];
#pragma unroll
        for (int m = 4; m <= 32; m <<= 1) {
            a.x += __shfl_xor(a.x, m);
            a.y += __shfl_xor(a.y, m);
            a.z += __shfl_xor(a.z, m);
            a.w += __shfl_xor(a.w, m);
        }
        if (lane < 4) *(float4*)&red[l][wv][lane * 4] = a;
    }
    __syncthreads();

    if (tid < 128) {
        const int l = tid >> 4;
        const int r = tid & 15;
        float s = 0.f;
#pragma unroll
        for (int k = 0; k < 8; ++k) s += red[l][k][r];
        part[(l * 512 + blockIdx.x) * 16 + r] = s;
    }
}

// ---------------------------------------------------------------------------
// K1b: tg[(l,h)][r] = sum of partials; one block per (l,h). Zeroes loss.
// ---------------------------------------------------------------------------
__global__ __launch_bounds__(64) void k_reduce_t(const float* __restrict__ part,
                                                 float* __restrict__ tg,
                                                 float* __restrict__ loss) {
    const int b = blockIdx.x;
    if (b == 0 && threadIdx.x == 0) loss[0] = 0.f;
    const int t = b + 2;
    const int l = 30 - __clz(t);
    const int h = t - (2 << l);
    const int cnt = 256 >> l;
    const int c0  = h * cnt;
    const int r = threadIdx.x & 15;
    const int g = threadIdx.x >> 4;

    float s = 0.f;
    for (int c = c0 + g; c < c0 + cnt; c += 4)
        s += part[(l * 512 + c) * 16 + r];

    __shared__ float red[64];
    red[threadIdx.x] = s;
    __syncthreads();
    if (threadIdx.x < 16)
        tg[((2 << l) - 2 + h) * 16 + r] = red[r] + red[16 + r] + red[32 + r] + red[48 + r];
}

// ---------------------------------------------------------------------------
// K2: w[i] = [L (L^T x)]_i + 1e-4*x[i] + sum_l u_l[i][:] . t_{l, sibling}
// Register-prefetched u (2 groups of 4 levels x 4 float4) to keep 16 loads
// in flight; group A latency hides under the staging barrier, group B under
// the leaf 32-FMA LDS pass.
// ---------------------------------------------------------------------------
__global__ __launch_bounds__(256) void k_apply(const float* __restrict__ leaf, P8 u,
                                               const float* __restrict__ z,
                                               const float* __restrict__ tg,
                                               float* __restrict__ w,
                                               float* __restrict__ y) {
    __shared__ float Lp[8 * 1056];
    __shared__ float xl[256];
    __shared__ float t32[8][32];
    __shared__ float tl[8][16];

    const int tid  = threadIdx.x;
    const int base = blockIdx.x * 256;
    const size_t i = (size_t)(base + tid);

    const float4* Lg = (const float4*)(leaf + (size_t)base * 32);
#pragma unroll
    for (int k = 0; k < 8; ++k) {
        const int fi = tid + k * 256;
        const float4 val = Lg[fi];
        const int lb  = fi >> 8;
        const int off = (fi & 255) * 4;
        const int row = off >> 5;
        const int col = off & 31;
        float* d = &Lp[lb * 1056 + row * 33 + col];
        d[0] = val.x; d[1] = val.y; d[2] = val.z; d[3] = val.w;
    }
    xl[tid] = z[base + tid];
    if (tid < 128) {
        const int l = tid >> 4;
        const int r = tid & 15;
        const int h = base >> (17 - l);
        tl[l][r] = tg[(((2 << l) - 2) + (h ^ 1)) * 16 + r];
    }

    // prefetch u levels 0..3 into registers (16 independent 16B loads);
    // their latency drains together with the staging loads at the barrier.
    float4 ua[4][4];
#pragma unroll
    for (int l = 0; l < 4; ++l) {
        const float4* up = (const float4*)(u.p[l] + i * RANK);
#pragma unroll
        for (int k = 0; k < 4; ++k) ua[l][k] = up[k];
    }
    __syncthreads();

    // t32 = L^T x  (column-parallel, pad-33 keeps it conflict-free)
    {
        const int lb = tid >> 5;
        const int c  = tid & 31;
        const float* Lb = &Lp[lb * 1056];
        const float* xb = &xl[lb * 32];
        float s = 0.f;
#pragma unroll
        for (int row = 0; row < 32; ++row)
            s += Lb[row * 33 + c] * xb[row];
        t32[lb][c] = s;
    }

    // group A FMAs (data already resident in regs; tl is stable since barrier)
    float accs[8];
#pragma unroll
    for (int l = 0; l < 4; ++l) {
        const float4 t0 = *(const float4*)&tl[l][0];
        const float4 t1 = *(const float4*)&tl[l][4];
        const float4 t2 = *(const float4*)&tl[l][8];
        const float4 t3 = *(const float4*)&tl[l][12];
        accs[l] = ua[l][0].x * t0.x + ua[l][0].y * t0.y + ua[l][0].z * t0.z + ua[l][0].w * t0.w
                + ua[l][1].x * t1.x + ua[l][1].y * t1.y + ua[l][1].z * t1.z + ua[l][1].w * t1.w
                + ua[l][2].x * t2.x + ua[l][2].y * t2.y + ua[l][2].z * t2.z + ua[l][2].w * t2.w
                + ua[l][3].x * t3.x + ua[l][3].y * t3.y + ua[l][3].z * t3.z + ua[l][3].w * t3.w;
    }
    __syncthreads();

    // issue group B loads (levels 4..7), then hide their latency under the
    // leaf row pass (32 LDS FMAs)
#pragma unroll
    for (int l = 0; l < 4; ++l) {
        const float4* up = (const float4*)(u.p[l + 4] + i * RANK);
#pragma unroll
        for (int k = 0; k < 4; ++k) ua[l][k] = up[k];
    }

    float acc;
    {
        const int lb = tid >> 5;
        const float* Lb = &Lp[lb * 1056 + (tid & 31) * 33];
        acc = 1e-4f * xl[tid];
#pragma unroll
        for (int c8 = 0; c8 < 8; ++c8) {
            const float4 tt = *(const float4*)&t32[lb][c8 * 4];
            acc += Lb[c8 * 4 + 0] * tt.x + Lb[c8 * 4 + 1] * tt.y
                 + Lb[c8 * 4 + 2] * tt.z + Lb[c8 * 4 + 3] * tt.w;
        }
    }

#pragma unroll
    for (int l = 0; l < 4; ++l) {
        const float4 t0 = *(const float4*)&tl[l + 4][0];
        const float4 t1 = *(const float4*)&tl[l + 4][4];
        const float4 t2 = *(const float4*)&tl[l + 4][8];
        const float4 t3 = *(const float4*)&tl[l + 4][12];
        accs[l + 4] = ua[l][0].x * t0.x + ua[l][0].y * t0.y + ua[l][0].z * t0.z + ua[l][0].w * t0.w
                    + ua[l][1].x * t1.x + ua[l][1].y * t1.y + ua[l][1].z * t1.z + ua[l][1].w * t1.w
                    + ua[l][2].x * t2.x + ua[l][2].y * t2.y + ua[l][2].z * t2.z + ua[l][2].w * t2.w
                    + ua[l][3].x * t3.x + ua[l][3].y * t3.y + ua[l][3].z * t3.z + ua[l][3].w * t3.w;
    }

    acc += ((accs[0] + accs[1]) + (accs[2] + accs[3]))
         + ((accs[4] + accs[5]) + (accs[6] + accs[7]));
    w[i] = acc;
    if (y) y[i] = 0.f;
}

// ---------------------------------------------------------------------------
// K3a: bucket-sort (row, val*w[col]) pairs. 512 threads (20 waves/CU).
// ---------------------------------------------------------------------------
__global__ __launch_bounds__(512) void k_bin(const int* __restrict__ idx,
                                             const float* __restrict__ vals,
                                             const float* __restrict__ w,
                                             unsigned long long* __restrict__ gpairs,
                                             int* __restrict__ gdesc) {
    __shared__ unsigned long long pairs[BPB];   // 16 KB
    __shared__ int hist[NBKT];
    __shared__ int scan[NBKT];
    __shared__ int cursor[NBKT];

    const int t  = threadIdx.x;
    const int bl = blockIdx.x;
    const int base = bl * BPB;

    if (t < NBKT) hist[t] = 0;
    __syncthreads();

    int   rows[4];
    float pv[4];
    {
        const int k = base + t * 4;
        const int4   r4 = *(const int4*)(idx + k);
        const int4   c4 = *(const int4*)(idx + NNZ_K + k);
        const float4 v4 = *(const float4*)(vals + k);
        rows[0] = r4.x; pv[0] = v4.x * w[c4.x];
        rows[1] = r4.y; pv[1] = v4.y * w[c4.y];
        rows[2] = r4.z; pv[2] = v4.z * w[c4.z];
        rows[3] = r4.w; pv[3] = v4.w * w[c4.w];
        atomicAdd(&hist[r4.x >> 10], 1);
        atomicAdd(&hist[r4.y >> 10], 1);
        atomicAdd(&hist[r4.z >> 10], 1);
        atomicAdd(&hist[r4.w >> 10], 1);
    }
    __syncthreads();

    // inclusive Hillis-Steele scan over 256 buckets (first 256 threads)
    int cnt = 0;
    if (t < NBKT) { cnt = hist[t]; scan[t] = cnt; }
    __syncthreads();
    for (int off = 1; off < NBKT; off <<= 1) {
        int add = 0;
        if (t >= off && t < NBKT) add = scan[t - off];
        __syncthreads();
        if (t < NBKT) scan[t] += add;
        __syncthreads();
    }
    if (t < NBKT) {
        const int st = scan[t] - cnt;          // exclusive start
        gdesc[t * NB + bl] = st | (cnt << 16); // transposed: coalesced in k_accum
        cursor[t] = st;
    }
    __syncthreads();

#pragma unroll
    for (int i = 0; i < 4; ++i) {
        const int b   = rows[i] >> 10;
        const int pos = atomicAdd(&cursor[b], 1);
        pairs[pos] = ((unsigned long long)__float_as_uint(pv[i]) << 32) | (unsigned)rows[i];
    }
    __syncthreads();

    // fully-coalesced block-contiguous write-out
    const ulonglong2* ps = (const ulonglong2*)pairs;
    ulonglong2*       pd = (ulonglong2*)(gpairs + (size_t)bl * BPB);
#pragma unroll
    for (int i = 0; i < 2; ++i)
        pd[i * 512 + t] = ps[i * 512 + t];
}

// ---------------------------------------------------------------------------
// K3b: block b accumulates its 1024 rows in LDS from all NB segments, then
// computes sum((y-z)^2). 1024 threads: 1 segment/thread, 1 row/thread.
// ---------------------------------------------------------------------------
__global__ __launch_bounds__(1024) void k_accum(const unsigned long long* __restrict__ gpairs,
                                                const int* __restrict__ gdesc,
                                                const float* __restrict__ z,
                                                float* __restrict__ loss) {
    __shared__ float acc[RPB];
    __shared__ float red[16];
    const int t = threadIdx.x;
    const int b = blockIdx.x;
    acc[t] = 0.f;
    __syncthreads();

    if (t < NB) {
        const int d  = gdesc[b * NB + t];
        const int st = d & 0xffff;
        const int c  = d >> 16;
        const unsigned long long* p = gpairs + (size_t)t * BPB + st;
        for (int j = 0; j < c; ++j) {
            const unsigned long long pr = p[j];
            atomicAdd(&acc[(int)(pr & 1023u)], __uint_as_float((unsigned)(pr >> 32)));
        }
    }
    __syncthreads();

    const float d = acc[t] - z[b * RPB + t];
    float s = d * d;
#pragma unroll
    for (int m = 32; m >= 1; m >>= 1) s += __shfl_down(s, m);
    if ((t & 63) == 0) red[t >> 6] = s;
    __syncthreads();
    if (t == 0) {
        float tt = 0.f;
#pragma unroll
        for (int i = 0; i < 16; ++i) tt += red[i];
        atomicAdd(loss, tt);
    }
}

// --------------------------- fallback path (small ws) ----------------------
__global__ __launch_bounds__(256) void k_spmv(const int* __restrict__ idx,
                                              const float* __restrict__ vals,
                                              const float* __restrict__ w,
                                              float* __restrict__ y) {
    const int k = (blockIdx.x * 256 + threadIdx.x) * 4;
    const int4   r4 = *(const int4*)(idx + k);
    const int4   c4 = *(const int4*)(idx + NNZ_K + k);
    const float4 v4 = *(const float4*)(vals + k);
    atomicAdd(&y[r4.x], v4.x * w[c4.x]);
    atomicAdd(&y[r4.y], v4.y * w[c4.y]);
    atomicAdd(&y[r4.z], v4.z * w[c4.z]);
    atomicAdd(&y[r4.w], v4.w * w[c4.w]);
}

__global__ __launch_bounds__(256) void k_loss(const float* __restrict__ y,
                                              const float* __restrict__ z,
                                              float* __restrict__ loss) {
    const int i = blockIdx.x * 256 + threadIdx.x;
    const float4 a = ((const float4*)y)[i];
    const float4 b = ((const float4*)z)[i];
    const float dx = a.x - b.x, dy = a.y - b.y, dz = a.z - b.z, dw = a.w - b.w;
    float s = dx * dx + dy * dy + dz * dz + dw * dw;
#pragma unroll
    for (int m = 32; m >= 1; m >>= 1) s += __shfl_down(s, m);
    __shared__ float r4s[4];
    const int lane = threadIdx.x & 63, wv = threadIdx.x >> 6;
    if (lane == 0) r4s[wv] = s;
    __syncthreads();
    if (threadIdx.x == 0) atomicAdd(loss, r4s[0] + r4s[1] + r4s[2] + r4s[3]);
}

__global__ void k_fin(const float* __restrict__ loss, float* __restrict__ out) {
    out[0] = loss[0] * (1.0f / (float)NN);
}

// ---------------------------------------------------------------------------
extern "C" void kernel_launch(void* const* d_in, const int* in_sizes, int n_in,
                              void* d_out, int out_size, void* d_ws, size_t ws_size,
                              hipStream_t stream) {
    const float* leaf = (const float*)d_in[0];
    P8 u, v;
    for (int l = 0; l < 8; ++l) {
        u.p[l] = (const float*)d_in[1 + 2 * l];
        v.p[l] = (const float*)d_in[2 + 2 * l];
    }
    const int*   Aidx  = (const int*)d_in[17];
    const float* Avals = (const float*)d_in[18];
    const float* z     = (const float*)d_in[19];

    float* ws   = (float*)d_ws;
    // layout (floats): unchanged from previous version
    float* part  = ws;                     // 65536
    float* tg    = ws + 65536;             // 8192
    float* loss  = ws + 73728;             // 1 (+pad to 73792)
    float* w     = ws + 73792;             // 262144 -> end 335936
    int*   gdesc = (int*)(ws + 335936);    // NBKT*NB = 163840 -> end 499776
    unsigned long long* gpairs = (unsigned long long*)(ws + 499776); // NB*BPB*8B
    const size_t need_main = (size_t)(499776 + (size_t)NB * BPB * 2) * 4;

    k_levels_t<<<NN / 512, 512, 0, stream>>>(v, z, part);
    k_reduce_t<<<510, 64, 0, stream>>>(part, tg, loss);

    if (ws_size >= need_main) {
        k_apply<<<NN / 256, 256, 0, stream>>>(leaf, u, z, tg, w, nullptr);
        k_bin  <<<NB, 512, 0, stream>>>(Aidx, Avals, w, gpairs, gdesc);
        k_accum<<<NBKT, 1024, 0, stream>>>(gpairs, gdesc, z, loss);
    } else {
        float* y = ws + 335936;            // fallback: y where desc/pairs were
        k_apply<<<NN / 256, 256, 0, stream>>>(leaf, u, z, tg, w, y);
        k_spmv <<<NNZ_K / 1024, 256, 0, stream>>>(Aidx, Avals, w, y);
        k_loss <<<NN / 1024, 256, 0, stream>>>(y, z, loss);
    }
    k_fin<<<1, 1, 0, stream>>>(loss, (float*)d_out);
}